// Round 1
// baseline (1265.784 us; speedup 1.0000x reference)
//
#include <hip/hip_runtime.h>
#include <math.h>

#define N 256
#define Dd 128

__device__ __forceinline__ double inv2s2_of(int s){
    return (s==0)?0.5:(s==1)?5.0e-3:(s==2)?5.0e-5:5.0e-7;
}

// ---------------- gather: z1s = z1[perm1], z2s = z2[perm2] ----------------
__global__ void k_gather(const float* __restrict__ z1, const float* __restrict__ z2,
                         const int* __restrict__ p1, const int* __restrict__ p2,
                         float* __restrict__ z1s, float* __restrict__ z2s){
    int idx = blockIdx.x*256 + threadIdx.x;   // 0 .. 2*N*Dd-1
    int half = N*Dd;
    if (idx < half){
        int i = idx / Dd, t = idx % Dd;
        z1s[idx] = z1[p1[i]*Dd + t];
    } else {
        int j = idx - half;
        int i = j / Dd, t = j % Dd;
        z2s[j] = z2[p2[i]*Dd + t];
    }
}

// ---------------- pairwise squared distances (5 matrices) ----------------
// w=0 Da: (z1,z1)+(z2,z2)   [num dede]
// w=1 Db: (z1,z1s)+(z2,z2s) [num denu]
// w=2 Dc: (z2s,z2s)         [den dede]
// w=3 Dm: (z2s,z2)          [M]
// w=4 Du: (z1,z2)           [U]
__global__ void k_dist(const float* __restrict__ z1, const float* __restrict__ z2,
                       const float* __restrict__ z1s, const float* __restrict__ z2s,
                       float* __restrict__ Dmat){
    __shared__ float Xs[16][17], Ys[16][17];
    int w = blockIdx.z;
    const float *X1, *Y1, *X2, *Y2; int npair;
    switch(w){
        case 0: X1=z1;  Y1=z1;  X2=z2; Y2=z2;  npair=2; break;
        case 1: X1=z1;  Y1=z1s; X2=z2; Y2=z2s; npair=2; break;
        case 2: X1=z2s; Y1=z2s; X2=0;  Y2=0;   npair=1; break;
        case 3: X1=z2s; Y1=z2;  X2=0;  Y2=0;   npair=1; break;
        default:X1=z1;  Y1=z2;  X2=0;  Y2=0;   npair=1; break;
    }
    int tx = threadIdx.x, ty = threadIdx.y;
    int row = blockIdx.y*16 + ty, col = blockIdx.x*16 + tx;
    double acc = 0.0;
    for (int p = 0; p < npair; p++){
        const float* X = p ? X2 : X1;
        const float* Y = p ? Y2 : Y1;
        for (int c = 0; c < Dd; c += 16){
            __syncthreads();
            Xs[ty][tx] = X[(blockIdx.y*16+ty)*Dd + c + tx];
            Ys[ty][tx] = Y[(blockIdx.x*16+ty)*Dd + c + tx];
            __syncthreads();
            #pragma unroll
            for (int t = 0; t < 16; t++){
                float d = Xs[ty][t] - Ys[tx][t];
                acc += (double)d * (double)d;
            }
        }
    }
    Dmat[w*N*N + row*N + col] = (float)acc;
}

// ---------------- kernel matrices: A (f64, +lam on diag), M/U (f32) ----------------
// blockIdx.y = bm: s = bm&3, type = bm>>2 (0:Aden<-Dc, 1:Anum<-Da, 2:M<-Dm, 3:U<-Du)
__global__ void k_kermat(const float* __restrict__ Dmat,
                         double* __restrict__ Aden, double* __restrict__ Anum,
                         float* __restrict__ M4, float* __restrict__ U4){
    int bm = blockIdx.y; int s = bm & 3; int type = bm >> 2;
    int row = blockIdx.x, k = threadIdx.x;
    int dsel = (type==0) ? 2 : (type==1) ? 0 : (type==2) ? 3 : 4;
    double v = exp(-inv2s2_of(s) * (double)Dmat[dsel*N*N + row*N + k]);
    int o = s*N*N + row*N + k;
    if (type == 0){ if (k == row) v += 1.0e-3; Aden[o] = v; }
    else if (type == 1){ if (k == row) v += 1.0e-3; Anum[o] = v; }
    else if (type == 2){ M4[o] = (float)v; }
    else { U4[o] = (float)v; }
}

// ---------------- b_num[s][j] = sum_k exp(-c*Db[j][k]) ----------------
__global__ void k_bnum(const float* __restrict__ Dmat, double* __restrict__ bnum){
    __shared__ double red[256];
    int s = blockIdx.y, j = blockIdx.x, k = threadIdx.x;
    red[k] = exp(-inv2s2_of(s) * (double)Dmat[1*N*N + j*N + k]);
    __syncthreads();
    for (int st = 128; st > 0; st >>= 1){
        if (k < st) red[k] += red[k + st];
        __syncthreads();
    }
    if (k == 0) bnum[s*N + j] = red[0];
}

// ---------------- symmetric Gauss-Jordan sweep inversion, G = A^{-1} (f32) ----------
// One block per matrix (8 total: 4 den + 4 num). Packed lower triangle lives in
// registers (float4 "slots"), padded to 4; pair-balanced rows (pg, 255-pg) per
// 8-thread group -> each thread owns <=9 float4 slots. Per pivot step: publish
// column j to 1KB LDS, barrier, rank-1 update own registers (branchless selects
// handle row j / col j transform), barrier.
__launch_bounds__(1024, 1)
__global__ void k_sweep(const double* __restrict__ Aden, const double* __restrict__ Anum,
                        float* __restrict__ Gden, float* __restrict__ Gnum){
    __shared__ __align__(16) float cj[256];
    int mat = blockIdx.x;
    const double* Asrc = (mat < 4) ? (Aden + mat*N*N) : (Anum + (mat-4)*N*N);
    float* Gdst = (mat < 4) ? (Gden + mat*N*N) : (Gnum + (mat-4)*N*N);
    int tid = threadIdx.x;
    int pg = tid >> 3, sub = tid & 7;
    int rA = pg, rB = 255 - pg;
    int A4 = (rA + 4) >> 2;        // float4 slots of row rA (len rA+1)
    int B4 = (rB + 4) >> 2;        // float4 slots of row rB (len rB+1)
    int total4 = A4 + B4;          // 65 or 66

    int srow[9], skb[9]; bool svalid[9]; float4 val[9];
    #pragma unroll
    for (int t = 0; t < 9; t++){
        int s = sub*9 + t;
        bool valid = (s < total4);
        int row = (s < A4) ? rA : rB;
        int kb  = (s < A4) ? (s << 2) : ((s - A4) << 2);
        if (!valid){ row = 0; kb = 0; }
        srow[t] = row; skb[t] = kb; svalid[t] = valid;
        float4 v = make_float4(0.f,0.f,0.f,0.f);
        if (valid){
            int len = row + 1;
            if (kb+0 < len) v.x = (float)Asrc[row*N + kb+0];
            if (kb+1 < len) v.y = (float)Asrc[row*N + kb+1];
            if (kb+2 < len) v.z = (float)Asrc[row*N + kb+2];
            if (kb+3 < len) v.w = (float)Asrc[row*N + kb+3];
        }
        val[t] = v;
    }

    for (int j = 0; j < N; j++){
        __syncthreads();   // previous step's cj reads complete
        // publish column j (row-j entries k<=j, plus (i,j) for i>j)
        #pragma unroll
        for (int t = 0; t < 9; t++){
            if (!svalid[t]) continue;
            int row = srow[t], kb = skb[t];
            if (row == j){
                if (kb+0 <= j) cj[kb+0] = val[t].x;
                if (kb+1 <= j) cj[kb+1] = val[t].y;
                if (kb+2 <= j) cj[kb+2] = val[t].z;
                if (kb+3 <= j) cj[kb+3] = val[t].w;
            } else if (row > j && kb <= j && j < kb+4){
                int c = j - kb;
                float pv = (c==0) ? val[t].x : (c==1) ? val[t].y : (c==2) ? val[t].z : val[t].w;
                cj[row] = pv;
            }
        }
        __syncthreads();
        float d = cj[j];
        float invd = 1.0f / d;
        #pragma unroll
        for (int t = 0; t < 9; t++){
            int row = srow[t], kb = skb[t];
            float s_r = cj[row] * invd;
            float4 c4 = *(const float4*)&cj[kb];
            float4 v = val[t];
            bool rj = (row == j);
            v.x = rj ? ((kb+0==j) ? -invd : c4.x*invd) : ((kb+0==j) ? s_r : v.x - s_r*c4.x);
            v.y = rj ? ((kb+1==j) ? -invd : c4.y*invd) : ((kb+1==j) ? s_r : v.y - s_r*c4.y);
            v.z = rj ? ((kb+2==j) ? -invd : c4.z*invd) : ((kb+2==j) ? s_r : v.z - s_r*c4.z);
            v.w = rj ? ((kb+3==j) ? -invd : c4.w*invd) : ((kb+3==j) ? s_r : v.w - s_r*c4.w);
            val[t] = v;
        }
    }
    // write out G = -swept (full symmetric)
    #pragma unroll
    for (int t = 0; t < 9; t++){
        if (!svalid[t]) continue;
        int row = srow[t], kb = skb[t], len = row + 1;
        float vv[4] = {val[t].x, val[t].y, val[t].z, val[t].w};
        for (int c = 0; c < 4; c++){
            int k = kb + c;
            if (k >= len) break;
            float g = -vv[c];
            Gdst[row*N + k] = g;
            Gdst[k*N + row] = g;
        }
    }
}

// ---------------- B = M * U^T (f32 in, f64 accum/out), batched over sigma --------
__global__ void k_gemm_nt(const float* __restrict__ M4, const float* __restrict__ U4,
                          double* __restrict__ Bmat){
    int s = blockIdx.z;
    const float* Mp = M4 + s*N*N;
    const float* Up = U4 + s*N*N;
    double* Bp = Bmat + s*N*N;
    __shared__ float Ms[32][33], Us[32][33];
    int tx = threadIdx.x, ty = threadIdx.y;
    int tid = ty*16 + tx;
    int bj = blockIdx.y*32, bi = blockIdx.x*32;
    double a00=0, a01=0, a10=0, a11=0;
    for (int kc = 0; kc < N; kc += 32){
        __syncthreads();
        #pragma unroll
        for (int l = 0; l < 4; l++){
            int e = tid + l*256; int r = e >> 5, c = e & 31;
            Ms[r][c] = Mp[(bj+r)*N + kc + c];
            Us[r][c] = Up[(bi+r)*N + kc + c];
        }
        __syncthreads();
        #pragma unroll
        for (int k = 0; k < 32; k++){
            float x0 = Ms[2*ty][k], x1 = Ms[2*ty+1][k];
            float y0 = Us[2*tx][k], y1 = Us[2*tx+1][k];
            a00 += (double)x0*y0; a01 += (double)x0*y1;
            a10 += (double)x1*y0; a11 += (double)x1*y1;
        }
    }
    Bp[(bj+2*ty  )*N + bi+2*tx  ] = a00;
    Bp[(bj+2*ty  )*N + bi+2*tx+1] = a01;
    Bp[(bj+2*ty+1)*N + bi+2*tx  ] = a10;
    Bp[(bj+2*ty+1)*N + bi+2*tx+1] = a11;
}

// ---------------- X0 = G * B  (G f32, B f64 -> X0 f32, f64 accum) ----------------
__global__ void k_gemm_x0(const float* __restrict__ Gden, const double* __restrict__ Bmat,
                          float* __restrict__ X0){
    int s = blockIdx.z;
    const float* Gp = Gden + s*N*N;
    const double* Bp = Bmat + s*N*N;
    float* Xp = X0 + s*N*N;
    __shared__ float Gs[32][33];
    __shared__ double Bs[32][33];
    int tx = threadIdx.x, ty = threadIdx.y;
    int tid = ty*16 + tx;
    int bj = blockIdx.y*32, bi = blockIdx.x*32;
    double a00=0, a01=0, a10=0, a11=0;
    for (int kc = 0; kc < N; kc += 32){
        __syncthreads();
        #pragma unroll
        for (int l = 0; l < 4; l++){
            int e = tid + l*256; int r = e >> 5, c = e & 31;
            Gs[r][c] = Gp[(bj+r)*N + kc + c];
            Bs[r][c] = Bp[(kc+r)*N + bi + c];
        }
        __syncthreads();
        #pragma unroll
        for (int k = 0; k < 32; k++){
            float x0 = Gs[2*ty][k], x1 = Gs[2*ty+1][k];
            double y0 = Bs[k][2*tx], y1 = Bs[k][2*tx+1];
            a00 += (double)x0*y0; a01 += (double)x0*y1;
            a10 += (double)x1*y0; a11 += (double)x1*y1;
        }
    }
    Xp[(bj+2*ty  )*N + bi+2*tx  ] = (float)a00;
    Xp[(bj+2*ty  )*N + bi+2*tx+1] = (float)a01;
    Xp[(bj+2*ty+1)*N + bi+2*tx  ] = (float)a10;
    Xp[(bj+2*ty+1)*N + bi+2*tx+1] = (float)a11;
}

// ---------------- R = B - A * X0  (A f64, X0 f32 -> R f32, f64 accum) ------------
__global__ void k_gemm_r(const double* __restrict__ Aden, const float* __restrict__ X0,
                         const double* __restrict__ Bmat, float* __restrict__ Rm){
    int s = blockIdx.z;
    const double* Ap = Aden + s*N*N;
    const float* Xp = X0 + s*N*N;
    const double* Bp = Bmat + s*N*N;
    float* Rp = Rm + s*N*N;
    __shared__ double As[32][33];
    __shared__ float Xs[32][33];
    int tx = threadIdx.x, ty = threadIdx.y;
    int tid = ty*16 + tx;
    int bj = blockIdx.y*32, bi = blockIdx.x*32;
    double a00=0, a01=0, a10=0, a11=0;
    for (int kc = 0; kc < N; kc += 32){
        __syncthreads();
        #pragma unroll
        for (int l = 0; l < 4; l++){
            int e = tid + l*256; int r = e >> 5, c = e & 31;
            As[r][c] = Ap[(bj+r)*N + kc + c];
            Xs[r][c] = Xp[(kc+r)*N + bi + c];
        }
        __syncthreads();
        #pragma unroll
        for (int k = 0; k < 32; k++){
            double x0 = As[2*ty][k], x1 = As[2*ty+1][k];
            double y0 = (double)Xs[k][2*tx], y1 = (double)Xs[k][2*tx+1];
            a00 += x0*y0; a01 += x0*y1;
            a10 += x1*y0; a11 += x1*y1;
        }
    }
    int r0 = bj+2*ty, c0 = bi+2*tx;
    Rp[(r0  )*N + c0  ] = (float)(Bp[(r0  )*N + c0  ] - a00);
    Rp[(r0  )*N + c0+1] = (float)(Bp[(r0  )*N + c0+1] - a01);
    Rp[(r0+1)*N + c0  ] = (float)(Bp[(r0+1)*N + c0  ] - a10);
    Rp[(r0+1)*N + c0+1] = (float)(Bp[(r0+1)*N + c0+1] - a11);
}

// ---------------- X = X0 + G * R  (all f32, f64 accum) ----------------
__global__ void k_gemm_x(const float* __restrict__ Gden, const float* __restrict__ Rm,
                         const float* __restrict__ X0, float* __restrict__ Xm){
    int s = blockIdx.z;
    const float* Gp = Gden + s*N*N;
    const float* Rp = Rm + s*N*N;
    const float* X0p = X0 + s*N*N;
    float* Xp = Xm + s*N*N;
    __shared__ float Gs[32][33], Rs[32][33];
    int tx = threadIdx.x, ty = threadIdx.y;
    int tid = ty*16 + tx;
    int bj = blockIdx.y*32, bi = blockIdx.x*32;
    double a00=0, a01=0, a10=0, a11=0;
    for (int kc = 0; kc < N; kc += 32){
        __syncthreads();
        #pragma unroll
        for (int l = 0; l < 4; l++){
            int e = tid + l*256; int r = e >> 5, c = e & 31;
            Gs[r][c] = Gp[(bj+r)*N + kc + c];
            Rs[r][c] = Rp[(kc+r)*N + bi + c];
        }
        __syncthreads();
        #pragma unroll
        for (int k = 0; k < 32; k++){
            float x0 = Gs[2*ty][k], x1 = Gs[2*ty+1][k];
            float y0 = Rs[k][2*tx], y1 = Rs[k][2*tx+1];
            a00 += (double)x0*y0; a01 += (double)x0*y1;
            a10 += (double)x1*y0; a11 += (double)x1*y1;
        }
    }
    int r0 = bj+2*ty, c0 = bi+2*tx;
    Xp[(r0  )*N + c0  ] = (float)((double)X0p[(r0  )*N + c0  ] + a00);
    Xp[(r0  )*N + c0+1] = (float)((double)X0p[(r0  )*N + c0+1] + a01);
    Xp[(r0+1)*N + c0  ] = (float)((double)X0p[(r0+1)*N + c0  ] + a10);
    Xp[(r0+1)*N + c0+1] = (float)((double)X0p[(r0+1)*N + c0+1] + a11);
}

// ---------------- numerator solves: y = Gnum*b, + one IR step ----------------
__global__ void k_numsolve(const float* __restrict__ Gnum, const double* __restrict__ Anum,
                           const double* __restrict__ bnum, float* __restrict__ rnum){
    __shared__ double y0[256], rr[256], bsh[256];
    int s = blockIdx.x, j = threadIdx.x;
    const float* Gp = Gnum + s*N*N;
    const double* Ap = Anum + s*N*N;
    const double* bp = bnum + s*N;
    bsh[j] = bp[j];
    __syncthreads();
    double acc = 0;
    for (int k = 0; k < N; k++) acc += (double)Gp[j*N+k] * bsh[k];
    y0[j] = acc;
    __syncthreads();
    acc = 0;
    for (int k = 0; k < N; k++) acc += Ap[j*N+k] * y0[k];
    rr[j] = bsh[j] - acc;
    __syncthreads();
    acc = 0;
    for (int k = 0; k < N; k++) acc += (double)Gp[j*N+k] * rr[k];
    rnum[s*N+j] = (float)(y0[j] + acc);
}

// ---------------- final loss ----------------
__global__ void k_loss(const float* __restrict__ Xm, const float* __restrict__ rnum,
                       float* __restrict__ out){
    __shared__ double red[256];
    int i = threadIdx.x;
    double dsum = 0;
    for (int j = 0; j < N; j++){
        float sx = 0.25f*(Xm[0*N*N + j*N + i] + Xm[1*N*N + j*N + i] +
                          Xm[2*N*N + j*N + i] + Xm[3*N*N + j*N + i]);
        dsum += (double)fmaxf(sx, 0.f);
    }
    double denum = dsum + (double)N * 1.0e-3;
    float ravg = 0.25f*(rnum[0*N+i] + rnum[1*N+i] + rnum[2*N+i] + rnum[3*N+i]);
    double rn = (double)fmaxf(ravg, 0.f) + 1.0e-3;
    red[i] = log(rn) + log(denum);
    __syncthreads();
    for (int st = 128; st > 0; st >>= 1){
        if (i < st) red[i] += red[i + st];
        __syncthreads();
    }
    if (i == 0) out[0] = (float)red[0];
}

extern "C" void kernel_launch(void* const* d_in, const int* in_sizes, int n_in,
                              void* d_out, int out_size, void* d_ws, size_t ws_size,
                              hipStream_t stream) {
    (void)in_sizes; (void)n_in; (void)out_size; (void)ws_size;
    const float* z1 = (const float*)d_in[0];
    const float* z2 = (const float*)d_in[1];
    const int*   p1 = (const int*)d_in[2];
    const int*   p2 = (const int*)d_in[3];
    float* out = (float*)d_out;

    char* w = (char*)d_ws;
    size_t o = 0;
    auto carve = [&](size_t bytes) -> char* {
        char* p = w + o;
        o += (bytes + 255) & ~(size_t)255;
        return p;
    };
    float*  z1s  = (float*) carve(N*Dd*sizeof(float));
    float*  z2s  = (float*) carve(N*Dd*sizeof(float));
    float*  Dmat = (float*) carve((size_t)5*N*N*sizeof(float));
    double* Aden = (double*)carve((size_t)4*N*N*sizeof(double));
    double* Anum = (double*)carve((size_t)4*N*N*sizeof(double));
    float*  M4   = (float*) carve((size_t)4*N*N*sizeof(float));
    float*  U4   = (float*) carve((size_t)4*N*N*sizeof(float));
    double* Bmat = (double*)carve((size_t)4*N*N*sizeof(double));
    float*  Gden = (float*) carve((size_t)4*N*N*sizeof(float));
    float*  Gnum = (float*) carve((size_t)4*N*N*sizeof(float));
    float*  X0   = (float*) carve((size_t)4*N*N*sizeof(float));
    float*  Rm   = (float*) carve((size_t)4*N*N*sizeof(float));
    float*  Xm   = (float*) carve((size_t)4*N*N*sizeof(float));
    double* bnum = (double*)carve((size_t)4*N*sizeof(double));
    float*  rnum = (float*) carve((size_t)4*N*sizeof(float));

    k_gather<<<dim3((2*N*Dd)/256), dim3(256), 0, stream>>>(z1, z2, p1, p2, z1s, z2s);
    k_dist<<<dim3(16,16,5), dim3(16,16), 0, stream>>>(z1, z2, z1s, z2s, Dmat);
    k_kermat<<<dim3(N,16), dim3(256), 0, stream>>>(Dmat, Aden, Anum, M4, U4);
    k_bnum<<<dim3(N,4), dim3(256), 0, stream>>>(Dmat, bnum);
    k_sweep<<<dim3(8), dim3(1024), 0, stream>>>(Aden, Anum, Gden, Gnum);
    k_gemm_nt<<<dim3(8,8,4), dim3(16,16), 0, stream>>>(M4, U4, Bmat);
    k_gemm_x0<<<dim3(8,8,4), dim3(16,16), 0, stream>>>(Gden, Bmat, X0);
    k_gemm_r<<<dim3(8,8,4), dim3(16,16), 0, stream>>>(Aden, X0, Bmat, Rm);
    k_gemm_x<<<dim3(8,8,4), dim3(16,16), 0, stream>>>(Gden, Rm, X0, Xm);
    k_numsolve<<<dim3(4), dim3(256), 0, stream>>>(Gnum, Anum, bnum, rnum);
    k_loss<<<dim3(1), dim3(256), 0, stream>>>(Xm, rnum, out);
}